// Round 11
// baseline (27.745 us; speedup 1.0000x reference)
//
#include <hip/hip_runtime.h>
#include <hip/hip_bf16.h>
#include <math.h>

#define NB 4
#define MA 256
#define NFS 128
#define KSEL 8
#define HID 256
#define NOUT 32
#define RCUT 5.0f
#define PI_F 3.14159265358979323846f

__device__ __forceinline__ float frcp(float x) { return __builtin_amdgcn_rcpf(x); }
__device__ __forceinline__ float fsqrt(float x) { return __builtin_amdgcn_sqrtf(x); }

// Kernel 1: 512 blocks = (rowgroup 0..255) x (half 0..1).
// Block computes 4 rows x 256 cols of (half==0 ? P : Q) over full f=0..127.
__global__ __launch_bounds__(256) void prep_kernel(
    const int* __restrict__ z, const float* __restrict__ r,
    const float* __restrict__ h, const float* __restrict__ Wa,
    const float* __restrict__ Wp1,
    float* __restrict__ out,
    float* __restrict__ a1, float* __restrict__ a2,
    float* __restrict__ P, float* __restrict__ Q) {
  const int b = blockIdx.x;
  const int half = b & 1;
  const int rg = b >> 1;
  const int r0 = 4 * rg;
  const int t = threadIdx.x;
  const int wave = t >> 6, lane = t & 63;
  const int c = t & 63, fq = t >> 6;

  __shared__ __align__(16) float hsh[4][NFS];
  __shared__ __align__(16) float psum[4][4][HID];   // 16 KB

  ((float2*)hsh)[t] = ((const float2*)(h + (size_t)r0 * NFS))[t];
  __syncthreads();

  if (half == 0) {
    const float h0 = hsh[wave][lane], h1 = hsh[wave][lane + 64];
    float p1 = h0 * Wa[lane]       + h1 * Wa[lane + 64];
    float p2 = h0 * Wa[NFS + lane] + h1 * Wa[NFS + lane + 64];
#pragma unroll
    for (int off = 32; off > 0; off >>= 1) {
      p1 += __shfl_down(p1, off);
      p2 += __shfl_down(p2, off);
    }
    if (lane == 0) { a1[r0 + wave] = p1; a2[r0 + wave] = p2; }
    if (t < 4)  out[r0 + t] = (float)z[r0 + t];
    if (t < 12) out[NB * MA + r0 * 3 + t] = r[r0 * 3 + t];
  }

  const float* __restrict__ Wbase = Wp1 + (size_t)(half ? NFS : 0) * HID;
  float4 acc[4] = {make_float4(0,0,0,0), make_float4(0,0,0,0),
                   make_float4(0,0,0,0), make_float4(0,0,0,0)};
#pragma unroll 4
  for (int ff = 0; ff < 32; ++ff) {
    const int f = fq * 32 + ff;
    const float4 w = *(const float4*)&Wbase[(size_t)f * HID + 4 * c];
#pragma unroll
    for (int rr = 0; rr < 4; ++rr) {
      const float hv = hsh[rr][f];
      acc[rr].x = fmaf(hv, w.x, acc[rr].x);
      acc[rr].y = fmaf(hv, w.y, acc[rr].y);
      acc[rr].z = fmaf(hv, w.z, acc[rr].z);
      acc[rr].w = fmaf(hv, w.w, acc[rr].w);
    }
  }
#pragma unroll
  for (int rr = 0; rr < 4; ++rr) *(float4*)&psum[fq][rr][4 * c] = acc[rr];
  __syncthreads();

  {
    const int r2 = t >> 6, c2 = t & 63;
    float4 s = *(const float4*)&psum[0][r2][4 * c2];
#pragma unroll
    for (int q = 1; q < 4; ++q) {
      const float4 p = *(const float4*)&psum[q][r2][4 * c2];
      s.x += p.x; s.y += p.y; s.z += p.z; s.w += p.w;
    }
    float* dst = (half ? Q : P) + (size_t)(r0 + r2) * HID + 4 * c2;
    *(float4*)dst = s;
  }
}

// Kernel 2: one block per (n,i). Wp2->LDS (vectorized) at top; g -> all-wave top8 ->
// hidden (rcp silu) -> layer2 broadcast (wreg from LDS) -> final (select tree, rcp).
__global__ __launch_bounds__(256) void main_kernel(
    const int* __restrict__ z, const float* __restrict__ r,
    const float* __restrict__ a1g, const float* __restrict__ a2g,
    const float* __restrict__ ba,
    const float* __restrict__ Pg, const float* __restrict__ Qg,
    const float* __restrict__ bp1,
    const float* __restrict__ Wp2g, const float* __restrict__ bp2,
    float* __restrict__ out) {
  const int row = blockIdx.x;   // n*MA + i
  const int n = row >> 8;
  const int i = row & 255;
  const int tid = threadIdx.x;
  const int lane = tid & 63;

  __shared__ float gsh[MA];                            // 1 KB
  __shared__ __align__(16) float wsh[HID * NOUT];      // 32 KB... no: 8192*4 = 32 KB
  __shared__ __align__(16) float hid_sh[KSEL][HID];    // 8 KB
  __shared__ float psum2[8][KSEL][NOUT];               // 8 KB

  // ---- stage Wp2 into LDS with wide loads (issued first, drains under g-phase) ----
  {
    const float4* __restrict__ src = (const float4*)Wp2g;
    float4* dst = (float4*)wsh;
#pragma unroll
    for (int j = 0; j < 8; ++j) dst[tid + 256 * j] = src[tid + 256 * j];
  }

  // ---- g for all j (this thread's j = tid) ----
  const float rix = r[row * 3 + 0], riy = r[row * 3 + 1], riz = r[row * 3 + 2];
  {
    const int jg = n * MA + tid;
    const float dx = r[jg * 3 + 0] - rix;
    const float dy = r[jg * 3 + 1] - riy;
    const float dz = r[jg * 3 + 2] - riz;
    const float d = fsqrt(dx * dx + dy * dy + dz * dz);
    const int mi = (z[row] > -1) ? 1 : 0;
    const int mj = (z[jg] > -1) ? 1 : 0;
    const int mask = max(mi * mj - ((tid == i) ? 1 : 0), 0);
    float g = 0.0f;
    if (mask) {
      const float cf = 0.5f * (__cosf(PI_F * fminf(d, RCUT) / RCUT) + 1.0f);
      g = __expf(a1g[row] + cf * a2g[jg] + ba[0]);
    }
    gsh[tid] = g;
  }
  // hoisted independent loads (overlap with topk chain below)
  const float pi_h = Pg[(size_t)row * HID + tid];
  const float bb_h = bp1[tid];
  __syncthreads();

  // layer-2 weights from LDS: 32 ds_read_b32, conflict-free (bank = l2o)
  const int l2o = tid & 31;
  const int l2c = tid >> 5;
  float wreg[32];
#pragma unroll
  for (int j = 0; j < 32; ++j) wreg[j] = wsh[(32 * l2c + j) * NOUT + l2o];

  // ---- ALL waves: denom + top-8 via shfl; att/idx wave-uniform ----
  float att[KSEL];
  int   idx[KSEL];
  {
    float v0 = gsh[lane];
    float v1 = gsh[lane + 64];
    float v2 = gsh[lane + 128];
    float v3 = gsh[lane + 192];
    float s = (v0 + v1) + (v2 + v3);
#pragma unroll
    for (int off = 32; off > 0; off >>= 1) s += __shfl_xor(s, off);
    const float rden = frcp(fmaxf(s, 1e-8f));
#pragma unroll
    for (int k = 0; k < KSEL; k++) {
      float bv = v0; int bi = lane;
      if (v1 > bv) { bv = v1; bi = lane + 64; }
      if (v2 > bv) { bv = v2; bi = lane + 128; }
      if (v3 > bv) { bv = v3; bi = lane + 192; }
#pragma unroll
      for (int off = 32; off > 0; off >>= 1) {
        const float ov = __shfl_xor(bv, off);
        const int oi = __shfl_xor(bi, off);
        if (ov > bv || (ov == bv && oi < bi)) { bv = ov; bi = oi; }
      }
      att[k] = bv * rden;
      idx[k] = __builtin_amdgcn_readfirstlane(bi);
      const int slot = bi >> 6, who = bi & 63;
      if (lane == who) {
        if (slot == 0) v0 = -1.0f;
        else if (slot == 1) v1 = -1.0f;
        else if (slot == 2) v2 = -1.0f;
        else v3 = -1.0f;
      }
    }
  }

  // ---- hidden: hid[k][tid] = silu(att_k*(P+Q) + b) with rcp-silu ----
  {
#pragma unroll
    for (int k = 0; k < KSEL; k++) {
      const float q = Qg[(size_t)(n * MA + idx[k]) * HID + tid];
      const float x = att[k] * (pi_h + q) + bb_h;
      hid_sh[k][tid] = x * frcp(1.0f + __expf(-x));
    }
  }
  __syncthreads();

  // ---- layer 2, broadcast scheme ----
  {
    float acc[KSEL];
#pragma unroll
    for (int k = 0; k < KSEL; ++k) acc[k] = 0.0f;
#pragma unroll
    for (int k = 0; k < KSEL; ++k) {
      const float4* __restrict__ hrow = (const float4*)&hid_sh[k][32 * l2c];
#pragma unroll
      for (int j4 = 0; j4 < 8; ++j4) {
        const float4 hv = hrow[j4];    // uniform across 32-lane group -> broadcast
        acc[k] = fmaf(hv.x, wreg[4 * j4 + 0],
                 fmaf(hv.y, wreg[4 * j4 + 1],
                 fmaf(hv.z, wreg[4 * j4 + 2],
                 fmaf(hv.w, wreg[4 * j4 + 3], acc[k]))));
      }
    }
#pragma unroll
    for (int k = 0; k < KSEL; ++k) psum2[l2c][k][l2o] = acc[k];
  }
  __syncthreads();

  // ---- final: thread (k2 = tid>>5, o = tid&31); idx via select tree; rcp norm ----
  {
    const int k2 = tid >> 5;
    const int o = tid & 31;
    float s = bp2[o];
#pragma unroll
    for (int cc = 0; cc < 8; ++cc) s += psum2[cc][k2][o];
    // explicit select tree over wave-uniform scalars (no runtime-indexed reg array)
    const int j01 = (k2 & 1) ? idx[1] : idx[0];
    const int j23 = (k2 & 1) ? idx[3] : idx[2];
    const int j45 = (k2 & 1) ? idx[5] : idx[4];
    const int j67 = (k2 & 1) ? idx[7] : idx[6];
    const int j03 = (k2 & 2) ? j23 : j01;
    const int j47 = (k2 & 2) ? j67 : j45;
    const int jsel = (k2 & 4) ? j47 : j03;
    const int jg = n * MA + jsel;
    const float dx = r[jg * 3 + 0] - rix;
    const float dy = r[jg * 3 + 1] - riy;
    const float dz = r[jg * 3 + 2] - riz;
    const float rn = frcp(fmaxf(fsqrt(dx * dx + dy * dy + dz * dz), 1e-4f));
    float* cb = out + NB * MA + NB * MA * 3 +
                ((size_t)row * KSEL + k2) * (NOUT * 3) + o * 3;
    cb[0] = s * (dx * rn);
    cb[1] = s * (dy * rn);
    cb[2] = s * (dz * rn);
  }
}

extern "C" void kernel_launch(void* const* d_in, const int* in_sizes, int n_in,
                              void* d_out, int out_size, void* d_ws, size_t ws_size,
                              hipStream_t stream) {
  const int*   z   = (const int*)d_in[0];
  const float* r   = (const float*)d_in[1];
  const float* h   = (const float*)d_in[2];
  const float* Wa  = (const float*)d_in[3];
  const float* ba  = (const float*)d_in[4];
  const float* Wp1 = (const float*)d_in[5];
  const float* bp1 = (const float*)d_in[6];
  const float* Wp2 = (const float*)d_in[7];
  const float* bp2 = (const float*)d_in[8];
  float* out = (float*)d_out;

  float* a1 = (float*)d_ws;                 // 1024
  float* a2 = a1 + NB * MA;                 // 1024
  float* P  = a2 + NB * MA;                 // 1024*256
  float* Q  = P + (size_t)NB * MA * HID;    // 1024*256

  prep_kernel<<<2 * NB * MA / 4, 256, 0, stream>>>(z, r, h, Wa, Wp1, out, a1, a2, P, Q);
  main_kernel<<<NB * MA, 256, 0, stream>>>(z, r, a1, a2, ba, P, Q, bp1, Wp2, bp2, out);
}

// Round 12
// 19.562 us; speedup vs baseline: 1.4183x; 1.4183x over previous
//
#include <hip/hip_runtime.h>
#include <hip/hip_bf16.h>
#include <math.h>

#define NB 4
#define MA 256
#define NFS 128
#define KSEL 8
#define HID 256
#define NOUT 32
#define RCUT 5.0f
#define PI_F 3.14159265358979323846f

__device__ __forceinline__ float frcp(float x) { return __builtin_amdgcn_rcpf(x); }
__device__ __forceinline__ float fsqrt(float x) { return __builtin_amdgcn_sqrtf(x); }

// Kernel 1: 512 blocks = (rowgroup 0..255) x (half 0..1).
// Block computes 4 rows x 256 cols of (half==0 ? P : Q) over full f=0..127.
__global__ __launch_bounds__(256) void prep_kernel(
    const int* __restrict__ z, const float* __restrict__ r,
    const float* __restrict__ h, const float* __restrict__ Wa,
    const float* __restrict__ Wp1,
    float* __restrict__ out,
    float* __restrict__ a1, float* __restrict__ a2,
    float* __restrict__ P, float* __restrict__ Q) {
  const int b = blockIdx.x;
  const int half = b & 1;
  const int rg = b >> 1;
  const int r0 = 4 * rg;
  const int t = threadIdx.x;
  const int wave = t >> 6, lane = t & 63;
  const int c = t & 63, fq = t >> 6;

  __shared__ __align__(16) float hsh[4][NFS];
  __shared__ __align__(16) float psum[4][4][HID];   // 16 KB

  ((float2*)hsh)[t] = ((const float2*)(h + (size_t)r0 * NFS))[t];
  __syncthreads();

  if (half == 0) {
    const float h0 = hsh[wave][lane], h1 = hsh[wave][lane + 64];
    float p1 = h0 * Wa[lane]       + h1 * Wa[lane + 64];
    float p2 = h0 * Wa[NFS + lane] + h1 * Wa[NFS + lane + 64];
#pragma unroll
    for (int off = 32; off > 0; off >>= 1) {
      p1 += __shfl_down(p1, off);
      p2 += __shfl_down(p2, off);
    }
    if (lane == 0) { a1[r0 + wave] = p1; a2[r0 + wave] = p2; }
    if (t < 4)  out[r0 + t] = (float)z[r0 + t];
    if (t < 12) out[NB * MA + r0 * 3 + t] = r[r0 * 3 + t];
  }

  const float* __restrict__ Wbase = Wp1 + (size_t)(half ? NFS : 0) * HID;
  float4 acc[4] = {make_float4(0,0,0,0), make_float4(0,0,0,0),
                   make_float4(0,0,0,0), make_float4(0,0,0,0)};
#pragma unroll 4
  for (int ff = 0; ff < 32; ++ff) {
    const int f = fq * 32 + ff;
    const float4 w = *(const float4*)&Wbase[(size_t)f * HID + 4 * c];
#pragma unroll
    for (int rr = 0; rr < 4; ++rr) {
      const float hv = hsh[rr][f];
      acc[rr].x = fmaf(hv, w.x, acc[rr].x);
      acc[rr].y = fmaf(hv, w.y, acc[rr].y);
      acc[rr].z = fmaf(hv, w.z, acc[rr].z);
      acc[rr].w = fmaf(hv, w.w, acc[rr].w);
    }
  }
#pragma unroll
  for (int rr = 0; rr < 4; ++rr) *(float4*)&psum[fq][rr][4 * c] = acc[rr];
  __syncthreads();

  {
    const int r2 = t >> 6, c2 = t & 63;
    float4 s = *(const float4*)&psum[0][r2][4 * c2];
#pragma unroll
    for (int q = 1; q < 4; ++q) {
      const float4 p = *(const float4*)&psum[q][r2][4 * c2];
      s.x += p.x; s.y += p.y; s.z += p.z; s.w += p.w;
    }
    float* dst = (half ? Q : P) + (size_t)(r0 + r2) * HID + 4 * c2;
    *(float4*)dst = s;
  }
}

// Kernel 2: one block per (n,i). g -> all-wave ballot top8 -> hidden -> layer2 -> final.
__global__ __launch_bounds__(256) void main_kernel(
    const int* __restrict__ z, const float* __restrict__ r,
    const float* __restrict__ a1g, const float* __restrict__ a2g,
    const float* __restrict__ ba,
    const float* __restrict__ Pg, const float* __restrict__ Qg,
    const float* __restrict__ bp1,
    const float* __restrict__ Wp2g, const float* __restrict__ bp2,
    float* __restrict__ out) {
  const int row = blockIdx.x;   // n*MA + i
  const int n = row >> 8;
  const int i = row & 255;
  const int tid = threadIdx.x;
  const int lane = tid & 63;

  __shared__ float gsh[MA];                            // 1 KB
  __shared__ __align__(16) float hid_sh[KSEL][HID];    // 8 KB
  __shared__ float psum2[8][KSEL][NOUT];               // 8 KB

  // layer-2 roles; one-pass Wp2 register staging issued EARLY (drains under g+topk)
  const int l2o = tid & 31;
  const int l2c = tid >> 5;
  float wreg[32];
#pragma unroll
  for (int j = 0; j < 32; ++j) wreg[j] = Wp2g[(size_t)(32 * l2c + j) * NOUT + l2o];

  // ---- g for all j (this thread's j = tid) ----
  const float rix = r[row * 3 + 0], riy = r[row * 3 + 1], riz = r[row * 3 + 2];
  {
    const int jg = n * MA + tid;
    const float dx = r[jg * 3 + 0] - rix;
    const float dy = r[jg * 3 + 1] - riy;
    const float dz = r[jg * 3 + 2] - riz;
    const float d = fsqrt(dx * dx + dy * dy + dz * dz);
    const int mi = (z[row] > -1) ? 1 : 0;
    const int mj = (z[jg] > -1) ? 1 : 0;
    const int mask = max(mi * mj - ((tid == i) ? 1 : 0), 0);
    float g = 0.0f;
    if (mask) {
      const float cf = 0.5f * (__cosf(PI_F * fminf(d, RCUT) / RCUT) + 1.0f);
      g = __expf(a1g[row] + cf * a2g[jg] + ba[0]);
    }
    gsh[tid] = g;
  }
  // hoisted independent loads (overlap with topk chain below)
  const float pi_h = Pg[(size_t)row * HID + tid];
  const float bb_h = bp1[tid];
  __syncthreads();

  // ---- ALL waves: denom + top-8; value-only butterfly + ballot index recovery ----
  float att[KSEL];
  int   idx[KSEL];
  {
    float v0 = gsh[lane];
    float v1 = gsh[lane + 64];
    float v2 = gsh[lane + 128];
    float v3 = gsh[lane + 192];
    float s = (v0 + v1) + (v2 + v3);
#pragma unroll
    for (int off = 32; off > 0; off >>= 1) s += __shfl_xor(s, off);
    const float rden = frcp(fmaxf(s, 1e-8f));
#pragma unroll
    for (int k = 0; k < KSEL; k++) {
      // global max value (6 shuffles, 1 v_max each)
      float bv = fmaxf(fmaxf(v0, v1), fmaxf(v2, v3));
#pragma unroll
      for (int off = 32; off > 0; off >>= 1) bv = fmaxf(bv, __shfl_xor(bv, off));
      // exact argmax with smallest-index tie-break via ballots (no DS ops)
      const unsigned long long b0 = __ballot(v0 == bv);
      const unsigned long long b1 = __ballot(v1 == bv);
      const unsigned long long b2 = __ballot(v2 == bv);
      const unsigned long long b3 = __ballot(v3 == bv);
      const int j0 = b0 ? __builtin_ctzll(b0)       : 1024;
      const int j1 = b1 ? __builtin_ctzll(b1) + 64  : 1024;
      const int j2 = b2 ? __builtin_ctzll(b2) + 128 : 1024;
      const int j3 = b3 ? __builtin_ctzll(b3) + 192 : 1024;
      const int bi = min(min(j0, j1), min(j2, j3));
      att[k] = bv * rden;
      idx[k] = __builtin_amdgcn_readfirstlane(bi);
      const int slot = bi >> 6, who = bi & 63;
      if (lane == who) {
        if (slot == 0) v0 = -1.0f;
        else if (slot == 1) v1 = -1.0f;
        else if (slot == 2) v2 = -1.0f;
        else v3 = -1.0f;
      }
    }
  }

  // ---- hidden: hid[k][tid] = silu(att_k*(P+Q) + b) with rcp-silu ----
  {
#pragma unroll
    for (int k = 0; k < KSEL; k++) {
      const float q = Qg[(size_t)(n * MA + idx[k]) * HID + tid];
      const float x = att[k] * (pi_h + q) + bb_h;
      hid_sh[k][tid] = x * frcp(1.0f + __expf(-x));
    }
  }
  __syncthreads();

  // ---- layer 2, broadcast scheme ----
  {
    float acc[KSEL];
#pragma unroll
    for (int k = 0; k < KSEL; ++k) acc[k] = 0.0f;
#pragma unroll
    for (int k = 0; k < KSEL; ++k) {
      const float4* __restrict__ hrow = (const float4*)&hid_sh[k][32 * l2c];
#pragma unroll
      for (int j4 = 0; j4 < 8; ++j4) {
        const float4 hv = hrow[j4];    // uniform across 32-lane group -> broadcast
        acc[k] = fmaf(hv.x, wreg[4 * j4 + 0],
                 fmaf(hv.y, wreg[4 * j4 + 1],
                 fmaf(hv.z, wreg[4 * j4 + 2],
                 fmaf(hv.w, wreg[4 * j4 + 3], acc[k]))));
      }
    }
#pragma unroll
    for (int k = 0; k < KSEL; ++k) psum2[l2c][k][l2o] = acc[k];
  }
  __syncthreads();

  // ---- final: thread (k2 = tid>>5, o = tid&31); select-tree idx; rcp norm ----
  {
    const int k2 = tid >> 5;
    const int o = tid & 31;
    float s = bp2[o];
#pragma unroll
    for (int cc = 0; cc < 8; ++cc) s += psum2[cc][k2][o];
    const int j01 = (k2 & 1) ? idx[1] : idx[0];
    const int j23 = (k2 & 1) ? idx[3] : idx[2];
    const int j45 = (k2 & 1) ? idx[5] : idx[4];
    const int j67 = (k2 & 1) ? idx[7] : idx[6];
    const int j03 = (k2 & 2) ? j23 : j01;
    const int j47 = (k2 & 2) ? j67 : j45;
    const int jsel = (k2 & 4) ? j47 : j03;
    const int jg = n * MA + jsel;
    const float dx = r[jg * 3 + 0] - rix;
    const float dy = r[jg * 3 + 1] - riy;
    const float dz = r[jg * 3 + 2] - riz;
    const float rn = frcp(fmaxf(fsqrt(dx * dx + dy * dy + dz * dz), 1e-4f));
    float* cb = out + NB * MA + NB * MA * 3 +
                ((size_t)row * KSEL + k2) * (NOUT * 3) + o * 3;
    cb[0] = s * (dx * rn);
    cb[1] = s * (dy * rn);
    cb[2] = s * (dz * rn);
  }
}

extern "C" void kernel_launch(void* const* d_in, const int* in_sizes, int n_in,
                              void* d_out, int out_size, void* d_ws, size_t ws_size,
                              hipStream_t stream) {
  const int*   z   = (const int*)d_in[0];
  const float* r   = (const float*)d_in[1];
  const float* h   = (const float*)d_in[2];
  const float* Wa  = (const float*)d_in[3];
  const float* ba  = (const float*)d_in[4];
  const float* Wp1 = (const float*)d_in[5];
  const float* bp1 = (const float*)d_in[6];
  const float* Wp2 = (const float*)d_in[7];
  const float* bp2 = (const float*)d_in[8];
  float* out = (float*)d_out;

  float* a1 = (float*)d_ws;                 // 1024
  float* a2 = a1 + NB * MA;                 // 1024
  float* P  = a2 + NB * MA;                 // 1024*256
  float* Q  = P + (size_t)NB * MA * HID;    // 1024*256

  prep_kernel<<<2 * NB * MA / 4, 256, 0, stream>>>(z, r, h, Wa, Wp1, out, a1, a2, P, Q);
  main_kernel<<<NB * MA, 256, 0, stream>>>(z, r, a1, a2, ba, P, Q, bp1, Wp2, bp2, out);
}